// Round 3
// baseline (4667.499 us; speedup 1.0000x reference)
//
#include <hip/hip_runtime.h>
#include <math.h>

#define B_   128
#define L_   256
#define DW_  100
#define DC_  30
#define HD_  200
#define NT_  18
#define SG   16
#define KP0  160   // padded K for layer-0 GEMM (130 -> 160)
#define KP1  416   // padded K for layer-1 GEMM (400 -> 416)

typedef _Float16 half8 __attribute__((ext_vector_type(8)));
typedef _Float16 half4 __attribute__((ext_vector_type(4)));
typedef float    f32x4 __attribute__((ext_vector_type(4)));

__device__ __forceinline__ float frcp_(float x) { return __builtin_amdgcn_rcpf(x); }
__device__ __forceinline__ float sigm_(float x) { return frcp_(1.0f + __expf(-x)); }
__device__ __forceinline__ float tanh_(float x) { return 1.0f - 2.0f * frcp_(1.0f + __expf(2.0f * x)); }

// ---------------- embedding gather -> fp16 x (B*L, KP0), pads zeroed
__global__ void k_embed(const int* __restrict__ words, const int* __restrict__ caps,
                        const float* __restrict__ wemb, const float* __restrict__ cemb,
                        _Float16* __restrict__ x) {
    int pos = blockIdx.x;
    int w = words[pos], c = caps[pos];
    _Float16* xp = x + (size_t)pos * KP0;
    for (int t = threadIdx.x; t < KP0; t += blockDim.x) {
        float v = 0.f;
        if (t < DW_) v = wemb[(size_t)w * DW_ + t];
        else if (t < DW_ + DC_) v = cemb[(size_t)c * DC_ + (t - DW_)];
        xp[t] = (_Float16)v;
    }
}

// ---------------- W_ih prep: src (800,K) fp32 -> dst fp16 (1600, Kpad), col = colOff + 4*jh + g
__global__ void k_perm_ih16(const float* __restrict__ src, _Float16* __restrict__ dst,
                            int K, int Kpad, int colOff) {
    int i = blockIdx.x * blockDim.x + threadIdx.x;
    if (i >= 800 * Kpad) return;
    int r = i / Kpad, k = i - r * Kpad;
    int jh = r % 200, g = r / 200;
    int col = colOff + (jh << 2) + g;
    dst[(size_t)col * Kpad + k] = (k < K) ? (_Float16)src[(size_t)r * K + k] : (_Float16)0.f;
}

__global__ void k_bias_perm(const float* bi_f, const float* bh_f,
                            const float* bi_b, const float* bh_b, float* bias) {
    int j = blockIdx.x * blockDim.x + threadIdx.x;
    if (j >= 1600) return;
    int dir = j / 800, r = j - dir * 800;
    int col = dir * 800 + ((r % 200) << 2) + (r / 200);
    bias[col] = dir ? (bi_b[r] + bh_b[r]) : (bi_f[r] + bh_f[r]);
}

__global__ void k_wlog(const float* __restrict__ Wf, const float* __restrict__ bfv,
                       const float* __restrict__ Wb, const float* __restrict__ bbv,
                       float* __restrict__ wlog, float* __restrict__ blog) {
    int i = blockIdx.x * blockDim.x + threadIdx.x;
    if (i < NT_ * 400) {
        int t = i / 400, k = i - t * 400;
        wlog[i] = (k < HD_) ? Wf[t * HD_ + k] : Wb[t * HD_ + (k - HD_)];
    }
    if (i < NT_) blog[i] = bfv[i] + bbv[i];
}

// ---------------- MFMA fp16 GEMM: C(M,1600) = A(M,Kpad) @ Bt(1600,Kpad)^T + bias
// BM=128, BN=64, BK=32; 256 threads = 4 waves; wave: 64x32 subtile
__global__ __launch_bounds__(256) void k_gemm16(const _Float16* __restrict__ A,
                                                const _Float16* __restrict__ Bt,
                                                const float* __restrict__ bias,
                                                _Float16* __restrict__ C,
                                                int Kpad) {
    __shared__ __align__(16) _Float16 sA[128 * 40];
    __shared__ __align__(16) _Float16 sB[64 * 40];
    const int tid = threadIdx.x;
    const int w = tid >> 6, l = tid & 63, l15 = l & 15, lq = l >> 4;
    const int m0 = blockIdx.y * 128, n0 = blockIdx.x * 64;
    const int rw = (w >> 1) * 64, cw = (w & 1) * 32;
    f32x4 acc[4][2];
    #pragma unroll
    for (int i = 0; i < 4; i++)
        #pragma unroll
        for (int j = 0; j < 2; j++) acc[i][j] = f32x4{0.f, 0.f, 0.f, 0.f};

    for (int k0 = 0; k0 < Kpad; k0 += 32) {
        {
            int m = tid >> 1, c = (tid & 1) << 4;
            const _Float16* ap = A + (size_t)(m0 + m) * Kpad + k0 + c;
            *(half8*)&sA[m * 40 + c]     = *(const half8*)ap;
            *(half8*)&sA[m * 40 + c + 8] = *(const half8*)(ap + 8);
        }
        {
            int n = tid >> 2, k8 = (tid & 3) << 3;
            *(half8*)&sB[n * 40 + k8] = *(const half8*)&Bt[(size_t)(n0 + n) * Kpad + k0 + k8];
        }
        __syncthreads();
        half8 aF[4], bF[2];
        #pragma unroll
        for (int i = 0; i < 4; i++) aF[i] = *(const half8*)&sA[(rw + i * 16 + l15) * 40 + lq * 8];
        #pragma unroll
        for (int j = 0; j < 2; j++) bF[j] = *(const half8*)&sB[(cw + j * 16 + l15) * 40 + lq * 8];
        #pragma unroll
        for (int i = 0; i < 4; i++)
            #pragma unroll
            for (int j = 0; j < 2; j++)
                acc[i][j] = __builtin_amdgcn_mfma_f32_16x16x32_f16(aF[i], bF[j], acc[i][j], 0, 0, 0);
        __syncthreads();
    }
    #pragma unroll
    for (int j = 0; j < 2; j++) {
        int n = n0 + cw + j * 16 + l15;
        float bv = bias[n];
        #pragma unroll
        for (int i = 0; i < 4; i++) {
            int mrow = m0 + rw + i * 16 + lq * 4;
            #pragma unroll
            for (int r = 0; r < 4; r++)
                C[(size_t)(mrow + r) * 1600 + n] = (_Float16)(acc[i][j][r] + bv);
        }
    }
}

// ---------------- single-barrier MFMA LSTM scan
// gates: (B,L,1600) fp16, cols = dir*800 + 4*h + gate(i,f,g,o)
// hout: fp16 (B*L, ldH); dir0 -> cols [0,200), dir1 -> [200,400); masked
__global__ __launch_bounds__(512, 2) void k_scan3(const _Float16* __restrict__ gates,
                                                  const float* __restrict__ Whh_f,
                                                  const float* __restrict__ Whh_b,
                                                  const int* __restrict__ seq_len,
                                                  _Float16* __restrict__ hout, int ldH) {
    const int dir = blockIdx.x & 1;
    const int b0  = (blockIdx.x >> 1) * SG;
    const int tid = threadIdx.x;
    const int w   = tid >> 6;
    const int l   = tid & 63;
    const int l15 = l & 15;
    const int lq  = l >> 4;

    __shared__ __align__(16) _Float16 hA[2 * 3712];        // ping-pong h state [p][m*232+k]
    __shared__ __align__(16) float    gbw[8][2240];        // wave-local gate sums [slot*320 + col16*20 + m]
    __shared__ __align__(16) _Float16 bEx[2 * 7 * 512];    // B-frags tiles 48,49
    __shared__ int ssl[SG];

    const float* W = dir ? Whh_b : Whh_f;
    const int nT = (w < 2) ? 7 : 6;

    // resident B-fragments: 6 register tiles per wave
    half8 Breg[6][7];
    #pragma unroll
    for (int i = 0; i < 6; i++) {
        int n  = (w * 6 + i) * 16 + l15;
        int jh = n >> 2, g = n & 3;
        const float* Wr = W + (size_t)(g * 200 + jh) * 200;
        #pragma unroll
        for (int kt = 0; kt < 7; kt++) {
            int k0 = kt * 32 + lq * 8;
            half8 f;
            #pragma unroll
            for (int j = 0; j < 8; j++) {
                int k = k0 + j;
                f[j] = (k < 200) ? (_Float16)Wr[k] : (_Float16)0.f;
            }
            Breg[i][kt] = f;
        }
    }
    if (w < 2) {
        int n  = (48 + w) * 16 + l15;
        int jh = n >> 2, g = n & 3;
        const float* Wr = W + (size_t)(g * 200 + jh) * 200;
        for (int kt = 0; kt < 7; kt++) {
            int k0 = kt * 32 + lq * 8;
            half8 f;
            for (int j = 0; j < 8; j++) {
                int k = k0 + j;
                f[j] = (k < 200) ? (_Float16)Wr[k] : (_Float16)0.f;
            }
            *(half8*)&bEx[(w * 7 + kt) * 512 + l * 8] = f;
        }
    }
    for (int i = tid; i < 2 * 3712; i += 512) hA[i] = (_Float16)0.f;
    if (tid < SG) ssl[tid] = seq_len[b0 + tid];

    // per-lane cell identity: batch m, hiddens hcol[i]
    const int hl = l15 >> 2;
    const int m  = lq * 4 + (l15 & 3);
    const int sl_m = seq_len[b0 + m];
    int hcol[7];
    #pragma unroll
    for (int i = 0; i < 7; i++) {
        int tile = (i < 6) ? (w * 6 + i) : (48 + w);
        hcol[i] = tile * 4 + hl;
    }
    float cc[7];
    #pragma unroll
    for (int i = 0; i < 7; i++) cc[i] = 0.f;

    __syncthreads();

    const size_t grow = (size_t)(b0 + m) * L_;
    half4 gn[7], gc[7];
    {   // prefetch t=0
        int row0 = dir ? ((0 < sl_m) ? sl_m - 1 : 0) : 0;
        const _Float16* gp = gates + (grow + row0) * 1600 + dir * 800;
        #pragma unroll
        for (int i = 0; i < 7; i++) if (i < nT) gn[i] = *(const half4*)(gp + 4 * hcol[i]);
    }

    const f32x4 Cz = {0.f, 0.f, 0.f, 0.f};
    for (int t = 0; t < L_; t++) {
        const int p = t & 1;
        #pragma unroll
        for (int i = 0; i < 7; i++) gc[i] = gn[i];

        // prefetch gates for t+1 (full step to hide HBM latency)
        if (t + 1 < L_) {
            int tn = t + 1;
            int rown = dir ? ((tn < sl_m) ? sl_m - 1 - tn : tn) : tn;
            const _Float16* gp = gates + (grow + rown) * 1600 + dir * 800;
            #pragma unroll
            for (int i = 0; i < 7; i++) if (i < nT) gn[i] = *(const half4*)(gp + 4 * hcol[i]);
        }

        // coalesced writeback of h(t-1) from stable buffer hA[p]
        if (t > 0) {
            int tp = t - 1;
            #pragma unroll
            for (int kk = 0; kk < 7; kk++) {
                int idx = tid + (kk << 9);
                if (idx < 3200) {
                    int b = idx / 200, hh = idx - b * 200;
                    int slb = ssl[b];
                    int row = dir ? ((tp < slb) ? slb - 1 - tp : tp) : tp;
                    _Float16 val = (tp < slb) ? hA[p * 3712 + b * 232 + hh] : (_Float16)0.f;
                    hout[((size_t)(b0 + b) * L_ + row) * ldH + dir * HD_ + hh] = val;
                }
            }
        }

        // MFMA: gatesum = h(t-1) @ Whh^T
        f32x4 C[6], Cx = Cz;
        #pragma unroll
        for (int i = 0; i < 6; i++) C[i] = Cz;
        #pragma unroll
        for (int kt = 0; kt < 7; kt++) {
            half8 aF = *(const half8*)&hA[p * 3712 + l15 * 232 + kt * 32 + lq * 8];
            #pragma unroll
            for (int i = 0; i < 6; i++)
                C[i] = __builtin_amdgcn_mfma_f32_16x16x32_f16(aF, Breg[i][kt], C[i], 0, 0, 0);
            if (w < 2) {
                half8 bF = *(const half8*)&bEx[(w * 7 + kt) * 512 + l * 8];
                Cx = __builtin_amdgcn_mfma_f32_16x16x32_f16(aF, bF, Cx, 0, 0, 0);
            }
        }
        #pragma unroll
        for (int i = 0; i < 6; i++) *(f32x4*)&gbw[w][i * 320 + l15 * 20 + lq * 4] = C[i];
        if (w < 2)                  *(f32x4*)&gbw[w][6 * 320 + l15 * 20 + lq * 4] = Cx;

        // wave-local nonlinearity (no barrier needed: reads what this wave wrote)
        #pragma unroll
        for (int i = 0; i < 7; i++) if (i < nT) {
            const float* gs = &gbw[w][i * 320 + (hl << 2) * 20 + m];
            float xi = gs[0]  + (float)gc[i][0];
            float xf = gs[20] + (float)gc[i][1];
            float xg = gs[40] + (float)gc[i][2];
            float xo = gs[60] + (float)gc[i][3];
            float cn = sigm_(xf) * cc[i] + sigm_(xi) * tanh_(xg);
            cc[i] = cn;
            float hv = sigm_(xo) * tanh_(cn);
            hA[(1 - p) * 3712 + m * 232 + hcol[i]] = (_Float16)hv;
        }
        __syncthreads();
    }
    // epilogue: write back h(L-1) from hA[0]
    {
        int tp = L_ - 1;
        #pragma unroll
        for (int kk = 0; kk < 7; kk++) {
            int idx = tid + (kk << 9);
            if (idx < 3200) {
                int b = idx / 200, hh = idx - b * 200;
                int slb = ssl[b];
                int row = dir ? ((tp < slb) ? slb - 1 - tp : tp) : tp;
                _Float16 val = (tp < slb) ? hA[0 * 3712 + b * 232 + hh] : (_Float16)0.f;
                hout[((size_t)(b0 + b) * L_ + row) * ldH + dir * HD_ + hh] = val;
            }
        }
    }
}

// ---------------- logits: (B*L,18) = h1(B*L,400 fp16) @ wlog^T + blog
__global__ __launch_bounds__(256) void k_logits(const _Float16* __restrict__ h1,
                                                const float* __restrict__ wlog,
                                                const float* __restrict__ blog,
                                                float* __restrict__ logits) {
    __shared__ float sh[8][400];
    __shared__ float sw[NT_ * 400];
    int p0 = blockIdx.x * 8;
    for (int i = threadIdx.x; i < 8 * 400; i += 256)
        sh[i / 400][i % 400] = (float)h1[(size_t)p0 * 400 + i];
    for (int i = threadIdx.x; i < NT_ * 400; i += 256) sw[i] = wlog[i];
    __syncthreads();
    if (threadIdx.x < 8 * NT_) {
        int pi = threadIdx.x / NT_, tg = threadIdx.x % NT_;
        float a = blog[tg];
        #pragma unroll 4
        for (int k = 0; k < 400; k++) a += sh[pi][k] * sw[tg * 400 + k];
        logits[((size_t)(p0 + pi)) * NT_ + tg] = a;
    }
}

// ---------------- CRF NLL per batch row
__global__ __launch_bounds__(64) void k_crf(const float* __restrict__ logits,
                                            const int* __restrict__ target,
                                            const int* __restrict__ seq_len,
                                            const float* __restrict__ trans,
                                            float* __restrict__ out) {
    int b = blockIdx.x, tid = threadIdx.x;
    __shared__ float str[NT_ * NT_];
    __shared__ float alpha[NT_];
    __shared__ float sgold[1];
    for (int i = tid; i < NT_ * NT_; i += 64) str[i] = trans[i];
    int sl = seq_len[b];
    const float* lg = logits + (size_t)b * L_ * NT_;
    const int* tg = target + (size_t)b * L_;
    if (tid < NT_) alpha[tid] = lg[tid];
    float gacc = 0.f;
    for (int t = tid; t < L_; t += 64) {
        if (t < sl) {
            gacc += lg[t * NT_ + tg[t]];
            if (t >= 1) gacc += trans[tg[t - 1] * NT_ + tg[t]];
        }
    }
    #pragma unroll
    for (int off = 32; off; off >>= 1) gacc += __shfl_down(gacc, off);
    if (tid == 0) sgold[0] = gacc;
    __syncthreads();
    for (int t = 1; t < L_; t++) {
        if (t < sl) {
            float v = 0.f;
            if (tid < NT_) {
                float mx = -1e30f;
                #pragma unroll
                for (int i = 0; i < NT_; i++) mx = fmaxf(mx, alpha[i] + str[i * NT_ + tid]);
                float s = 0.f;
                #pragma unroll
                for (int i = 0; i < NT_; i++) s += __expf(alpha[i] + str[i * NT_ + tid] - mx);
                v = mx + __logf(s) + lg[t * NT_ + tid];
            }
            __syncthreads();
            if (tid < NT_) alpha[tid] = v;
            __syncthreads();
        }
    }
    if (tid == 0) {
        float mx = -1e30f;
        for (int i = 0; i < NT_; i++) mx = fmaxf(mx, alpha[i]);
        float s = 0.f;
        for (int i = 0; i < NT_; i++) s += __expf(alpha[i] - mx);
        out[b] = (mx + __logf(s)) - sgold[0];
    }
}

extern "C" void kernel_launch(void* const* d_in, const int* in_sizes, int n_in,
                              void* d_out, int out_size, void* d_ws, size_t ws_size,
                              hipStream_t stream) {
    const int*   words  = (const int*)d_in[0];
    const int*   caps   = (const int*)d_in[1];
    const int*   seq    = (const int*)d_in[2];
    const int*   target = (const int*)d_in[3];
    const float* wemb   = (const float*)d_in[4];
    const float* cemb   = (const float*)d_in[5];
    const float* Wih0f  = (const float*)d_in[6];
    const float* Whh0f  = (const float*)d_in[7];
    const float* bih0f  = (const float*)d_in[8];
    const float* bhh0f  = (const float*)d_in[9];
    const float* Wih0b  = (const float*)d_in[10];
    const float* Whh0b  = (const float*)d_in[11];
    const float* bih0b  = (const float*)d_in[12];
    const float* bhh0b  = (const float*)d_in[13];
    const float* Wih1f  = (const float*)d_in[14];
    const float* Whh1f  = (const float*)d_in[15];
    const float* bih1f  = (const float*)d_in[16];
    const float* bhh1f  = (const float*)d_in[17];
    const float* Wih1b  = (const float*)d_in[18];
    const float* Whh1b  = (const float*)d_in[19];
    const float* bih1b  = (const float*)d_in[20];
    const float* bhh1b  = (const float*)d_in[21];
    const float* Wf     = (const float*)d_in[22];
    const float* bfv    = (const float*)d_in[23];
    const float* Wb     = (const float*)d_in[24];
    const float* bbv    = (const float*)d_in[25];
    const float* trans  = (const float*)d_in[26];

    char* base = (char*)d_ws;
    _Float16* gatesH = (_Float16*)(base + 0);                 // 104,857,600 B (32768x1600)
    _Float16* xbuf   = (_Float16*)(base + 104857600);         // 10,485,760 B (32768x160)
    _Float16* h0b    = (_Float16*)(base + 115343360);         // 27,262,976 B (32768x416)
    _Float16* h1b    = xbuf;  // 26,214,400 B needed; xbuf+h0 region dead by then
    float* logitsb   = (float*)(base + 142606336);            // 2,359,296 B
    _Float16* wihT0  = (_Float16*)(base + 144965632);         // 512,000 B (1600x160)
    _Float16* wihT1  = (_Float16*)(base + 145477632);         // 1,331,200 B (1600x416)
    float* bias0     = (float*)(base + 146808832);            // 6,400 B
    float* bias1     = (float*)(base + 146815232);            // 6,400 B
    float* wlog      = (float*)(base + 146821632);            // 28,800 B
    float* blog      = (float*)(base + 146850432);            // 128 B

    // --- weight prep
    k_perm_ih16<<<(800 * KP0 + 255) / 256, 256, 0, stream>>>(Wih0f, wihT0, 130, KP0, 0);
    k_perm_ih16<<<(800 * KP0 + 255) / 256, 256, 0, stream>>>(Wih0b, wihT0, 130, KP0, 800);
    k_perm_ih16<<<(800 * KP1 + 255) / 256, 256, 0, stream>>>(Wih1f, wihT1, 400, KP1, 0);
    k_perm_ih16<<<(800 * KP1 + 255) / 256, 256, 0, stream>>>(Wih1b, wihT1, 400, KP1, 800);
    k_bias_perm<<<7, 256, 0, stream>>>(bih0f, bhh0f, bih0b, bhh0b, bias0);
    k_bias_perm<<<7, 256, 0, stream>>>(bih1f, bhh1f, bih1b, bhh1b, bias1);
    k_wlog<<<(NT_ * 400 + 255) / 256, 256, 0, stream>>>(Wf, bfv, Wb, bbv, wlog, blog);

    // --- embeddings (fp16, padded)
    k_embed<<<B_ * L_, 128, 0, stream>>>(words, caps, wemb, cemb, xbuf);

    // zero h0 (its K-pad cols 400..415 must be 0 for the layer-1 GEMM)
    hipMemsetAsync(h0b, 0, (size_t)32768 * KP1 * sizeof(_Float16), stream);

    // --- layer 0
    k_gemm16<<<dim3(25, 256), 256, 0, stream>>>(xbuf, wihT0, bias0, gatesH, KP0);
    k_scan3<<<(B_ / SG) * 2, 512, 0, stream>>>(gatesH, Whh0f, Whh0b, seq, h0b, KP1);

    // --- layer 1
    k_gemm16<<<dim3(25, 256), 256, 0, stream>>>(h0b, wihT1, bias1, gatesH, KP1);
    k_scan3<<<(B_ / SG) * 2, 512, 0, stream>>>(gatesH, Whh1f, Whh1b, seq, h1b, 400);

    // --- logits + CRF
    k_logits<<<(B_ * L_) / 8, 256, 0, stream>>>(h1b, wlog, blog, logitsb);
    k_crf<<<B_, 64, 0, stream>>>(logitsb, target, seq, trans, (float*)d_out);
}

// Round 4
// 1482.263 us; speedup vs baseline: 3.1489x; 3.1489x over previous
//
#include <hip/hip_runtime.h>
#include <math.h>

#define B_   128
#define L_   256
#define DW_  100
#define DC_  30
#define HD_  200
#define NT_  18
#define SG   4     // batches per scan block
#define KP0  160   // padded K for layer-0 GEMM (130 -> 160)
#define KP1  416   // padded K for layer-1 GEMM (400 -> 416)

typedef _Float16 half8 __attribute__((ext_vector_type(8)));
typedef _Float16 half4 __attribute__((ext_vector_type(4)));
typedef float    f32x4 __attribute__((ext_vector_type(4)));

__device__ __forceinline__ float frcp_(float x) { return __builtin_amdgcn_rcpf(x); }
__device__ __forceinline__ float sigm_(float x) { return frcp_(1.0f + __expf(-x)); }
__device__ __forceinline__ float tanh_(float x) { return 1.0f - 2.0f * frcp_(1.0f + __expf(2.0f * x)); }

// ---------------- embedding gather -> fp16 x (B*L, KP0), pads zeroed
__global__ void k_embed(const int* __restrict__ words, const int* __restrict__ caps,
                        const float* __restrict__ wemb, const float* __restrict__ cemb,
                        _Float16* __restrict__ x) {
    int pos = blockIdx.x;
    int w = words[pos], c = caps[pos];
    _Float16* xp = x + (size_t)pos * KP0;
    for (int t = threadIdx.x; t < KP0; t += blockDim.x) {
        float v = 0.f;
        if (t < DW_) v = wemb[(size_t)w * DW_ + t];
        else if (t < DW_ + DC_) v = cemb[(size_t)c * DC_ + (t - DW_)];
        xp[t] = (_Float16)v;
    }
}

// ---------------- W_ih prep: src (800,K) fp32 -> dst fp16 (1600, Kpad), col = colOff + 4*jh + g
__global__ void k_perm_ih16(const float* __restrict__ src, _Float16* __restrict__ dst,
                            int K, int Kpad, int colOff) {
    int i = blockIdx.x * blockDim.x + threadIdx.x;
    if (i >= 800 * Kpad) return;
    int r = i / Kpad, k = i - r * Kpad;
    int jh = r % 200, g = r / 200;
    int col = colOff + (jh << 2) + g;
    dst[(size_t)col * Kpad + k] = (k < K) ? (_Float16)src[(size_t)r * K + k] : (_Float16)0.f;
}

__global__ void k_bias_perm(const float* bi_f, const float* bh_f,
                            const float* bi_b, const float* bh_b, float* bias) {
    int j = blockIdx.x * blockDim.x + threadIdx.x;
    if (j >= 1600) return;
    int dir = j / 800, r = j - dir * 800;
    int col = dir * 800 + ((r % 200) << 2) + (r / 200);
    bias[col] = dir ? (bi_b[r] + bh_b[r]) : (bi_f[r] + bh_f[r]);
}

__global__ void k_wlog(const float* __restrict__ Wf, const float* __restrict__ bfv,
                       const float* __restrict__ Wb, const float* __restrict__ bbv,
                       float* __restrict__ wlog, float* __restrict__ blog) {
    int i = blockIdx.x * blockDim.x + threadIdx.x;
    if (i < NT_ * 400) {
        int t = i / 400, k = i - t * 400;
        wlog[i] = (k < HD_) ? Wf[t * HD_ + k] : Wb[t * HD_ + (k - HD_)];
    }
    if (i < NT_) blog[i] = bfv[i] + bbv[i];
}

// ---------------- MFMA fp16 GEMM: C(M,1600) = A(M,Kpad) @ Bt(1600,Kpad)^T + bias
__global__ __launch_bounds__(256) void k_gemm16(const _Float16* __restrict__ A,
                                                const _Float16* __restrict__ Bt,
                                                const float* __restrict__ bias,
                                                _Float16* __restrict__ C,
                                                int Kpad) {
    __shared__ __align__(16) _Float16 sA[128 * 40];
    __shared__ __align__(16) _Float16 sB[64 * 40];
    const int tid = threadIdx.x;
    const int w = tid >> 6, l = tid & 63, l15 = l & 15, lq = l >> 4;
    const int m0 = blockIdx.y * 128, n0 = blockIdx.x * 64;
    const int rw = (w >> 1) * 64, cw = (w & 1) * 32;
    f32x4 acc[4][2];
    #pragma unroll
    for (int i = 0; i < 4; i++)
        #pragma unroll
        for (int j = 0; j < 2; j++) acc[i][j] = f32x4{0.f, 0.f, 0.f, 0.f};

    for (int k0 = 0; k0 < Kpad; k0 += 32) {
        {
            int m = tid >> 1, c = (tid & 1) << 4;
            const _Float16* ap = A + (size_t)(m0 + m) * Kpad + k0 + c;
            *(half8*)&sA[m * 40 + c]     = *(const half8*)ap;
            *(half8*)&sA[m * 40 + c + 8] = *(const half8*)(ap + 8);
        }
        {
            int n = tid >> 2, k8 = (tid & 3) << 3;
            *(half8*)&sB[n * 40 + k8] = *(const half8*)&Bt[(size_t)(n0 + n) * Kpad + k0 + k8];
        }
        __syncthreads();
        half8 aF[4], bF[2];
        #pragma unroll
        for (int i = 0; i < 4; i++) aF[i] = *(const half8*)&sA[(rw + i * 16 + l15) * 40 + lq * 8];
        #pragma unroll
        for (int j = 0; j < 2; j++) bF[j] = *(const half8*)&sB[(cw + j * 16 + l15) * 40 + lq * 8];
        #pragma unroll
        for (int i = 0; i < 4; i++)
            #pragma unroll
            for (int j = 0; j < 2; j++)
                acc[i][j] = __builtin_amdgcn_mfma_f32_16x16x32_f16(aF[i], bF[j], acc[i][j], 0, 0, 0);
        __syncthreads();
    }
    #pragma unroll
    for (int j = 0; j < 2; j++) {
        int n = n0 + cw + j * 16 + l15;
        float bv = bias[n];
        #pragma unroll
        for (int i = 0; i < 4; i++) {
            int mrow = m0 + rw + i * 16 + lq * 4;
            #pragma unroll
            for (int r = 0; r < 4; r++)
                C[(size_t)(mrow + r) * 1600 + n] = (_Float16)(acc[i][j][r] + bv);
        }
    }
}

// ---------------- MFMA LSTM scan v4: 64 blocks (32 batch-groups x 2 dirs), SG=4
// gates: (B,L,1600) fp16, cols = dir*800 + 4*h + gate(i,f,g,o)
// hout: fp16 (B*L, ldH); dir0 -> cols [0,200), dir1 -> [200,400); masked
__global__ __launch_bounds__(512, 2) void k_scan4(const _Float16* __restrict__ gates,
                                                  const float* __restrict__ Whh_f,
                                                  const float* __restrict__ Whh_b,
                                                  const int* __restrict__ seq_len,
                                                  _Float16* __restrict__ hout, int ldH) {
    const int dir = blockIdx.x & 1;
    const int b0  = (blockIdx.x >> 1) * SG;
    const int tid = threadIdx.x;
    const int w   = tid >> 6;
    const int l   = tid & 63;
    const int l15 = l & 15;
    const int lq  = l >> 4;

    __shared__ __align__(16) _Float16 hA[2][16 * 232];   // ping-pong h state [p][m*232+k]
    __shared__ __align__(16) float    gbw[8 * 476];      // gate sums [w*476 + i*68 + m*17 + col16]
    __shared__ __align__(16) _Float16 bEx[2 * 7 * 512];  // B-frags tiles 48,49
    __shared__ __align__(16) _Float16 glds[2][3200];     // staged gates [buf][m*800 + col]
    __shared__ int ssl[SG];

    const float* W = dir ? Whh_b : Whh_f;
    const int nT = (w < 2) ? 7 : 6;

    // resident B-fragments: 6 register tiles per wave + tiles 48/49 in LDS (waves 0,1)
    half8 Breg[6][7];
    #pragma unroll
    for (int i = 0; i < 6; i++) {
        int n  = (w * 6 + i) * 16 + l15;
        int jh = n >> 2, g = n & 3;
        const float* Wr = W + (size_t)(g * 200 + jh) * 200;
        #pragma unroll
        for (int kt = 0; kt < 7; kt++) {
            int k0 = kt * 32 + lq * 8;
            half8 f;
            #pragma unroll
            for (int j = 0; j < 8; j++) {
                int k = k0 + j;
                f[j] = (k < 200) ? (_Float16)Wr[k] : (_Float16)0.f;
            }
            Breg[i][kt] = f;
        }
    }
    if (w < 2) {
        int n  = (48 + w) * 16 + l15;
        int jh = n >> 2, g = n & 3;
        const float* Wr = W + (size_t)(g * 200 + jh) * 200;
        for (int kt = 0; kt < 7; kt++) {
            int k0 = kt * 32 + lq * 8;
            half8 f;
            for (int j = 0; j < 8; j++) {
                int k = k0 + j;
                f[j] = (k < 200) ? (_Float16)Wr[k] : (_Float16)0.f;
            }
            *(half8*)&bEx[(w * 7 + kt) * 512 + l * 8] = f;
        }
    }
    for (int i = tid; i < 2 * 16 * 232; i += 512) (&hA[0][0])[i] = (_Float16)0.f;
    if (tid < SG) ssl[tid] = seq_len[b0 + tid];

    // staging lane identity: unit v covers 4 rows x 100 x 16B
    const int  v    = tid;
    const bool stv  = v < 400;
    const int  m_st = v / 100;
    const int  u_st = v - m_st * 100;
    const int  sl_st = stv ? seq_len[b0 + m_st] : L_;
    const _Float16* gbase_st = gates + ((size_t)(b0 + m_st) * L_) * 1600 + dir * 800 + u_st * 8;

    // cell identities: lane owns cell cA = l, cell cB = l + 64 (if < nT*16)
    const int cA = l;
    const int cB = l + 64;
    const bool vB = cB < nT * 16;
    const int iA = cA >> 4,           nhA = (cA >> 2) & 3, mA = cA & 3;
    const int iB = cB >> 4,           nhB = (cB >> 2) & 3, mB = cB & 3;
    const int igA = (iA < 6) ? (w * 6 + iA) : (48 + w);
    const int igB = (iB < 6) ? (w * 6 + iB) : (48 + w);
    const int hAcol = igA * 4 + nhA;
    const int hBcol = igB * 4 + nhB;
    float csA = 0.f, csB = 0.f;

    // stage t=0
    half8 stg;
    if (stv) {
        int rn = dir ? ((sl_st > 0) ? sl_st - 1 : 0) : 0;
        stg = *(const half8*)(gbase_st + (size_t)rn * 1600);
        *(half8*)&glds[0][v * 8] = stg;
    }
    __syncthreads();

    const f32x4 Cz = {0.f, 0.f, 0.f, 0.f};
    for (int t = 0; t < L_; t++) {
        const int p = t & 1;

        // issue staging load for t+1 (committed to LDS at end of step)
        half8 stgn;
        const bool doStg = stv && (t + 1 < L_);
        if (doStg) {
            int tn = t + 1;
            int rn = dir ? ((tn < sl_st) ? sl_st - 1 - tn : tn) : tn;
            stgn = *(const half8*)(gbase_st + (size_t)rn * 1600);
        }

        // coalesced writeback of h(t-1) from hA[p]
        if (t > 0) {
            int tp = t - 1;
            #pragma unroll
            for (int kk = 0; kk < 2; kk++) {
                int idx = tid + (kk << 9);
                if (idx < 800) {
                    int b = (idx * 5243) >> 20;
                    int hh = idx - b * 200;
                    int slb = ssl[b];
                    int row = dir ? ((tp < slb) ? slb - 1 - tp : tp) : tp;
                    _Float16 val = (tp < slb) ? hA[p][b * 232 + hh] : (_Float16)0.f;
                    hout[((size_t)(b0 + b) * L_ + row) * ldH + dir * HD_ + hh] = val;
                }
            }
        }

        // MFMA: gatesum = h(t-1) @ Whh^T
        f32x4 C[7];
        #pragma unroll
        for (int i = 0; i < 7; i++) C[i] = Cz;
        #pragma unroll
        for (int kt = 0; kt < 7; kt++) {
            half8 aF = *(const half8*)&hA[p][l15 * 232 + kt * 32 + lq * 8];
            #pragma unroll
            for (int i = 0; i < 6; i++)
                C[i] = __builtin_amdgcn_mfma_f32_16x16x32_f16(aF, Breg[i][kt], C[i], 0, 0, 0);
            if (w < 2) {
                half8 bF = *(const half8*)&bEx[(w * 7 + kt) * 512 + l * 8];
                C[6] = __builtin_amdgcn_mfma_f32_16x16x32_f16(aF, bF, C[6], 0, 0, 0);
            }
        }
        // write gate sums (M=4: only rows 0..3 = lanes 0..15 hold data)
        if (l < 16) {
            #pragma unroll
            for (int i = 0; i < 7; i++) if (i < nT) {
                #pragma unroll
                for (int r = 0; r < 4; r++)
                    gbw[w * 476 + i * 68 + r * 17 + l15] = C[i][r];
            }
        }

        // wave-local nonlinearity (same-wave LDS, no barrier)
        {
            const float* gw = &gbw[w * 476 + iA * 68 + mA * 17 + nhA * 4];
            half4 gi4 = *(const half4*)&glds[p][mA * 800 + 4 * hAcol];
            float xi = gw[0] + (float)gi4[0];
            float xf = gw[1] + (float)gi4[1];
            float xg = gw[2] + (float)gi4[2];
            float xo = gw[3] + (float)gi4[3];
            float cn = sigm_(xf) * csA + sigm_(xi) * tanh_(xg);
            csA = cn;
            hA[1 - p][mA * 232 + hAcol] = (_Float16)(sigm_(xo) * tanh_(cn));
        }
        if (vB) {
            const float* gw = &gbw[w * 476 + iB * 68 + mB * 17 + nhB * 4];
            half4 gi4 = *(const half4*)&glds[p][mB * 800 + 4 * hBcol];
            float xi = gw[0] + (float)gi4[0];
            float xf = gw[1] + (float)gi4[1];
            float xg = gw[2] + (float)gi4[2];
            float xo = gw[3] + (float)gi4[3];
            float cn = sigm_(xf) * csB + sigm_(xi) * tanh_(xg);
            csB = cn;
            hA[1 - p][mB * 232 + hBcol] = (_Float16)(sigm_(xo) * tanh_(cn));
        }

        // commit staged gates for t+1 (vmcnt wait lands here, late in step)
        if (doStg) *(half8*)&glds[1 - p][v * 8] = stgn;

        __syncthreads();
    }
    // epilogue: write back h(L-1) from hA[0]
    {
        int tp = L_ - 1;
        #pragma unroll
        for (int kk = 0; kk < 2; kk++) {
            int idx = tid + (kk << 9);
            if (idx < 800) {
                int b = (idx * 5243) >> 20;
                int hh = idx - b * 200;
                int slb = ssl[b];
                int row = dir ? ((tp < slb) ? slb - 1 - tp : tp) : tp;
                _Float16 val = (tp < slb) ? hA[0][b * 232 + hh] : (_Float16)0.f;
                hout[((size_t)(b0 + b) * L_ + row) * ldH + dir * HD_ + hh] = val;
            }
        }
    }
}

// ---------------- logits: (B*L,18) = h1(B*L,400 fp16) @ wlog^T + blog
__global__ __launch_bounds__(256) void k_logits(const _Float16* __restrict__ h1,
                                                const float* __restrict__ wlog,
                                                const float* __restrict__ blog,
                                                float* __restrict__ logits) {
    __shared__ float sh[8][400];
    __shared__ float sw[NT_ * 400];
    int p0 = blockIdx.x * 8;
    for (int i = threadIdx.x; i < 8 * 400; i += 256)
        sh[i / 400][i % 400] = (float)h1[(size_t)p0 * 400 + i];
    for (int i = threadIdx.x; i < NT_ * 400; i += 256) sw[i] = wlog[i];
    __syncthreads();
    if (threadIdx.x < 8 * NT_) {
        int pi = threadIdx.x / NT_, tg = threadIdx.x % NT_;
        float a = blog[tg];
        #pragma unroll 4
        for (int k = 0; k < 400; k++) a += sh[pi][k] * sw[tg * 400 + k];
        logits[((size_t)(p0 + pi)) * NT_ + tg] = a;
    }
}

// ---------------- CRF NLL per batch row
__global__ __launch_bounds__(64) void k_crf(const float* __restrict__ logits,
                                            const int* __restrict__ target,
                                            const int* __restrict__ seq_len,
                                            const float* __restrict__ trans,
                                            float* __restrict__ out) {
    int b = blockIdx.x, tid = threadIdx.x;
    __shared__ float str[NT_ * NT_];
    __shared__ float alpha[NT_];
    __shared__ float sgold[1];
    for (int i = tid; i < NT_ * NT_; i += 64) str[i] = trans[i];
    int sl = seq_len[b];
    const float* lg = logits + (size_t)b * L_ * NT_;
    const int* tg = target + (size_t)b * L_;
    if (tid < NT_) alpha[tid] = lg[tid];
    float gacc = 0.f;
    for (int t = tid; t < L_; t += 64) {
        if (t < sl) {
            gacc += lg[t * NT_ + tg[t]];
            if (t >= 1) gacc += trans[tg[t - 1] * NT_ + tg[t]];
        }
    }
    #pragma unroll
    for (int off = 32; off; off >>= 1) gacc += __shfl_down(gacc, off);
    if (tid == 0) sgold[0] = gacc;
    __syncthreads();
    for (int t = 1; t < L_; t++) {
        if (t < sl) {
            float v = 0.f;
            if (tid < NT_) {
                float mx = -1e30f;
                #pragma unroll
                for (int i = 0; i < NT_; i++) mx = fmaxf(mx, alpha[i] + str[i * NT_ + tid]);
                float s = 0.f;
                #pragma unroll
                for (int i = 0; i < NT_; i++) s += __expf(alpha[i] + str[i * NT_ + tid] - mx);
                v = mx + __logf(s) + lg[t * NT_ + tid];
            }
            __syncthreads();
            if (tid < NT_) alpha[tid] = v;
            __syncthreads();
        }
    }
    if (tid == 0) {
        float mx = -1e30f;
        for (int i = 0; i < NT_; i++) mx = fmaxf(mx, alpha[i]);
        float s = 0.f;
        for (int i = 0; i < NT_; i++) s += __expf(alpha[i] - mx);
        out[b] = (mx + __logf(s)) - sgold[0];
    }
}

extern "C" void kernel_launch(void* const* d_in, const int* in_sizes, int n_in,
                              void* d_out, int out_size, void* d_ws, size_t ws_size,
                              hipStream_t stream) {
    const int*   words  = (const int*)d_in[0];
    const int*   caps   = (const int*)d_in[1];
    const int*   seq    = (const int*)d_in[2];
    const int*   target = (const int*)d_in[3];
    const float* wemb   = (const float*)d_in[4];
    const float* cemb   = (const float*)d_in[5];
    const float* Wih0f  = (const float*)d_in[6];
    const float* Whh0f  = (const float*)d_in[7];
    const float* bih0f  = (const float*)d_in[8];
    const float* bhh0f  = (const float*)d_in[9];
    const float* Wih0b  = (const float*)d_in[10];
    const float* Whh0b  = (const float*)d_in[11];
    const float* bih0b  = (const float*)d_in[12];
    const float* bhh0b  = (const float*)d_in[13];
    const float* Wih1f  = (const float*)d_in[14];
    const float* Whh1f  = (const float*)d_in[15];
    const float* bih1f  = (const float*)d_in[16];
    const float* bhh1f  = (const float*)d_in[17];
    const float* Wih1b  = (const float*)d_in[18];
    const float* Whh1b  = (const float*)d_in[19];
    const float* bih1b  = (const float*)d_in[20];
    const float* bhh1b  = (const float*)d_in[21];
    const float* Wf     = (const float*)d_in[22];
    const float* bfv    = (const float*)d_in[23];
    const float* Wb     = (const float*)d_in[24];
    const float* bbv    = (const float*)d_in[25];
    const float* trans  = (const float*)d_in[26];

    char* base = (char*)d_ws;
    _Float16* gatesH = (_Float16*)(base + 0);                 // 104,857,600 B (32768x1600)
    _Float16* xbuf   = (_Float16*)(base + 104857600);         // 10,485,760 B (32768x160)
    _Float16* h0b    = (_Float16*)(base + 115343360);         // 27,262,976 B (32768x416)
    _Float16* h1b    = xbuf;  // 26,214,400 B needed; xbuf+h0 region dead by then
    float* logitsb   = (float*)(base + 142606336);            // 2,359,296 B
    _Float16* wihT0  = (_Float16*)(base + 144965632);         // 512,000 B (1600x160)
    _Float16* wihT1  = (_Float16*)(base + 145477632);         // 1,331,200 B (1600x416)
    float* bias0     = (float*)(base + 146808832);            // 6,400 B
    float* bias1     = (float*)(base + 146815232);            // 6,400 B
    float* wlog      = (float*)(base + 146821632);            // 28,800 B
    float* blog      = (float*)(base + 146850432);            // 128 B

    // --- weight prep
    k_perm_ih16<<<(800 * KP0 + 255) / 256, 256, 0, stream>>>(Wih0f, wihT0, 130, KP0, 0);
    k_perm_ih16<<<(800 * KP0 + 255) / 256, 256, 0, stream>>>(Wih0b, wihT0, 130, KP0, 800);
    k_perm_ih16<<<(800 * KP1 + 255) / 256, 256, 0, stream>>>(Wih1f, wihT1, 400, KP1, 0);
    k_perm_ih16<<<(800 * KP1 + 255) / 256, 256, 0, stream>>>(Wih1b, wihT1, 400, KP1, 800);
    k_bias_perm<<<7, 256, 0, stream>>>(bih0f, bhh0f, bih0b, bhh0b, bias0);
    k_bias_perm<<<7, 256, 0, stream>>>(bih1f, bhh1f, bih1b, bhh1b, bias1);
    k_wlog<<<(NT_ * 400 + 255) / 256, 256, 0, stream>>>(Wf, bfv, Wb, bbv, wlog, blog);

    // --- embeddings (fp16, padded)
    k_embed<<<B_ * L_, 128, 0, stream>>>(words, caps, wemb, cemb, xbuf);

    // zero h0 (its K-pad cols 400..415 must be 0 for the layer-1 GEMM)
    hipMemsetAsync(h0b, 0, (size_t)32768 * KP1 * sizeof(_Float16), stream);

    // --- layer 0
    k_gemm16<<<dim3(25, 256), 256, 0, stream>>>(xbuf, wihT0, bias0, gatesH, KP0);
    k_scan4<<<(B_ / SG) * 2, 512, 0, stream>>>(gatesH, Whh0f, Whh0b, seq, h0b, KP1);

    // --- layer 1
    k_gemm16<<<dim3(25, 256), 256, 0, stream>>>(h0b, wihT1, bias1, gatesH, KP1);
    k_scan4<<<(B_ / SG) * 2, 512, 0, stream>>>(gatesH, Whh1f, Whh1b, seq, h1b, 400);

    // --- logits + CRF
    k_logits<<<(B_ * L_) / 8, 256, 0, stream>>>(h1b, wlog, blog, logitsb);
    k_crf<<<B_, 64, 0, stream>>>(logitsb, target, seq, trans, (float*)d_out);
}